// Round 7
// baseline (217.808 us; speedup 1.0000x reference)
//
#include <hip/hip_runtime.h>
#include <hip/hip_bf16.h>

// GCNConv: out = D * (A @ (D * (X@W))) + bias,  D = rsqrt(rowsum(A)+1)
// N=100000, E=640000, C=128.
// R2: CSR gather replaced atomic scatter (1285->317us).
// R3: bf16 MFMA GEMM (317->301us).
// R4: 1 atomic/edge CSR build, packed uint2 edges, bf16 Y (301->242us).
// R5: MLP unrolls in rank/place/gather (242->230us).
// R6: LDS-staged Wt in gemm (230->216us).
// R7: branch-free clamped 8-wide gather batch (8 Y-gathers in flight per
//     half-wave), straight-line gemm tile loop (clamped tile idx, no break),
//     wcvt folded into scan3.

#define N_CH 128
#define WT_LD 136  // padded LDS row stride (ushorts): 2 lanes/bank max (free)

typedef __attribute__((ext_vector_type(8))) short short8;
typedef __attribute__((ext_vector_type(4))) float f32x4;
typedef __attribute__((ext_vector_type(4))) unsigned short ushort4v;

__device__ inline unsigned short f2bf(float f) {
    unsigned u = __float_as_uint(f);
    return (unsigned short)((u + 0x7FFFu + ((u >> 16) & 1u)) >> 16);  // RNE
}
__device__ inline float bf2f(unsigned short h) {
    return __uint_as_float(((unsigned)h) << 16);
}

// ---- rank[e] = atomicAdd(&cnt[row[e]], 1); 8 edges/thread ----------------
__global__ __launch_bounds__(256) void rank_kernel(const int* __restrict__ row,
                                                   int* __restrict__ cnt,
                                                   int* __restrict__ rank, int E) {
    int e0 = blockIdx.x * 2048 + threadIdx.x;
#pragma unroll
    for (int j = 0; j < 8; ++j) {
        int e = e0 + j * 256;
        if (e < E) rank[e] = atomicAdd(&cnt[row[e]], 1);
    }
}

// ---- exclusive scan of cnt -> pos (2-level) ------------------------------
__global__ __launch_bounds__(256) void scan1_kernel(const int* __restrict__ cnt,
                                                    int* __restrict__ pos,
                                                    int* __restrict__ bsum, int N) {
    __shared__ int s[256];
    int t = threadIdx.x;
    int i = blockIdx.x * 256 + t;
    int v = (i < N) ? cnt[i] : 0;
    s[t] = v;
    __syncthreads();
    for (int off = 1; off < 256; off <<= 1) {
        int x = (t >= off) ? s[t - off] : 0;
        __syncthreads();
        s[t] += x;
        __syncthreads();
    }
    if (i < N) pos[i] = s[t] - v;
    if (t == 255) bsum[blockIdx.x] = s[t];
}

__global__ __launch_bounds__(512) void scan2_kernel(int* __restrict__ bsum, int nb) {
    __shared__ int s[512];
    int t = threadIdx.x;
    int v = (t < nb) ? bsum[t] : 0;
    s[t] = v;
    __syncthreads();
    for (int off = 1; off < 512; off <<= 1) {
        int x = (t >= off) ? s[t - off] : 0;
        __syncthreads();
        s[t] += x;
        __syncthreads();
    }
    if (t < nb) bsum[t] = s[t] - v;
}

// ---- scan3 + folded W convert/transpose ----------------------------------
__global__ __launch_bounds__(256) void scan3_kernel(int* __restrict__ pos,
                                                    const int* __restrict__ bsum, int N,
                                                    const float* __restrict__ W,
                                                    unsigned short* __restrict__ Wt) {
    int i = blockIdx.x * 256 + threadIdx.x;
    if (i < N) pos[i] += bsum[blockIdx.x];
    if (i < N_CH * N_CH) {
        int k = i >> 7, n = i & 127;
        Wt[n * N_CH + k] = f2bf(W[k * N_CH + n]);
    }
}

// ---- CSR place (no atomics): epack[pos[r]+rank[e]] = {col,val}; 4/thread -
__global__ __launch_bounds__(256) void place_kernel(const int* __restrict__ row,
                                                    const int* __restrict__ col,
                                                    const float* __restrict__ vals,
                                                    const int* __restrict__ pos,
                                                    const int* __restrict__ rank,
                                                    uint2* __restrict__ epack, int E) {
    int e0 = blockIdx.x * 1024 + threadIdx.x;
#pragma unroll
    for (int j = 0; j < 4; ++j) {
        int e = e0 + j * 256;
        if (e < E) {
            int r = row[e];
            int p = pos[r] + rank[e];
            epack[p] = make_uint2((unsigned)col[e], __float_as_uint(vals[e]));
        }
    }
}

// ---- dinv[n] = rsqrt(1 + sum of vals in row n) ---------------------------
__global__ __launch_bounds__(256) void dinv_kernel(const int* __restrict__ pos,
                                                   const uint2* __restrict__ epack,
                                                   float* __restrict__ dinv, int N, int E) {
    int n = blockIdx.x * 256 + threadIdx.x;
    if (n >= N) return;
    int start = pos[n];
    int end = (n + 1 < N) ? pos[n + 1] : E;
    float s = 0.f;
    for (int e = start; e < end; ++e) s += __uint_as_float(epack[e].y);
    dinv[n] = rsqrtf(s + 1.0f);
}

// ---- Ybf[n,:] = bf16( dinv[n] * (X[n,:] @ W) ), bf16 MFMA ----------------
// Block = 4 waves; Wt staged in LDS (padded, conflict-free). 2 tiles/wave,
// straight-line (tile idx clamped; duplicate tail writes are value-identical).
// C/D: col=lane&15, row=(lane>>4)*4+reg. Requires N % 16 == 0.
__global__ __launch_bounds__(256) void gemm_kernel(const float* __restrict__ X,
                                                   const unsigned short* __restrict__ Wt,
                                                   const float* __restrict__ dinv,
                                                   unsigned short* __restrict__ Ybf,
                                                   int tiles) {
    __shared__ unsigned short Wl[N_CH * WT_LD];  // 34 KB

    const int t = threadIdx.x;
    const short8* Wg = (const short8*)Wt;
#pragma unroll
    for (int j = 0; j < 8; ++j) {
        int idx = t + 256 * j;
        int r = idx >> 4, cc = idx & 15;
        *(short8*)(Wl + r * WT_LD + cc * 8) = Wg[idx];
    }
    __syncthreads();

    const int lane = t & 63;
    const int wv = t >> 6;
    const int m = lane & 15;
    const int q = lane >> 4;
    const int slot0 = blockIdx.x * 8 + wv * 2;

#pragma unroll
    for (int i = 0; i < 2; ++i) {
        int tile = slot0 + i;
        if (tile > tiles - 1) tile = tiles - 1;
        const int base = tile * 16;

        short8 a[4];
        const float* xrow = X + (size_t)(base + m) * N_CH + q * 8;
#pragma unroll
        for (int c = 0; c < 4; ++c) {
            f32x4 lo = *(const f32x4*)(xrow + c * 32);
            f32x4 hi = *(const f32x4*)(xrow + c * 32 + 4);
            short8 v;
            v[0] = (short)f2bf(lo[0]); v[1] = (short)f2bf(lo[1]);
            v[2] = (short)f2bf(lo[2]); v[3] = (short)f2bf(lo[3]);
            v[4] = (short)f2bf(hi[0]); v[5] = (short)f2bf(hi[1]);
            v[6] = (short)f2bf(hi[2]); v[7] = (short)f2bf(hi[3]);
            a[c] = v;
        }

        f32x4 acc[8];
#pragma unroll
        for (int tt = 0; tt < 8; ++tt) acc[tt] = (f32x4){0.f, 0.f, 0.f, 0.f};

#pragma unroll
        for (int tt = 0; tt < 8; ++tt) {
            const unsigned short* wrow = Wl + (tt * 16 + m) * WT_LD + q * 8;
#pragma unroll
            for (int c = 0; c < 4; ++c) {
                short8 b = *(const short8*)(wrow + c * 32);
                acc[tt] = __builtin_amdgcn_mfma_f32_16x16x32_bf16(a[c], b, acc[tt], 0, 0, 0);
            }
        }

        float ds[4];
#pragma unroll
        for (int r = 0; r < 4; ++r) ds[r] = dinv[base + q * 4 + r];

#pragma unroll
        for (int tt = 0; tt < 8; ++tt) {
#pragma unroll
            for (int r = 0; r < 4; ++r) {
                Ybf[(size_t)(base + q * 4 + r) * N_CH + tt * 16 + m] = f2bf(acc[tt][r] * ds[r]);
            }
        }
    }
}

// ---- gather: out[n,:] = dinv[n] * sum_e val_e * Y[col_e,:] + bias --------
// Half-wave per node. Branch-free 8-wide batches: indices clamped to end-1,
// out-of-range weights zeroed -> 8 independent Y gathers in flight.
__global__ __launch_bounds__(256) void gather_kernel(const int* __restrict__ pos,
                                                     const uint2* __restrict__ epack,
                                                     const unsigned short* __restrict__ Ybf,
                                                     const float* __restrict__ dinv,
                                                     const float* __restrict__ bias,
                                                     float* __restrict__ out, int N, int E) {
    unsigned gid = blockIdx.x * 256u + threadIdx.x;
    int n = gid >> 5;
    if (n >= N) return;
    int lane = gid & 31;
    int c = lane * 4;

    int e = pos[n];
    int end = (n + 1 < N) ? pos[n + 1] : E;

    float4 acc = make_float4(0.f, 0.f, 0.f, 0.f);
    if (e < end) {
        const int last = end - 1;
        do {
            uint2 p[8];
#pragma unroll
            for (int j = 0; j < 8; ++j) {
                int ej = e + j;
                ej = ej > last ? last : ej;
                p[j] = epack[ej];
            }
            ushort4v y[8];
#pragma unroll
            for (int j = 0; j < 8; ++j) {
                y[j] = *(const ushort4v*)(Ybf + (size_t)p[j].x * N_CH + c);
            }
#pragma unroll
            for (int j = 0; j < 8; ++j) {
                float v = (e + j <= last) ? __uint_as_float(p[j].y) : 0.f;
                acc.x += v * bf2f(y[j][0]);
                acc.y += v * bf2f(y[j][1]);
                acc.z += v * bf2f(y[j][2]);
                acc.w += v * bf2f(y[j][3]);
            }
            e += 8;
        } while (e < end);
    }

    float d = dinv[n];
    float4 b = ((const float4*)bias)[lane];
    float4 o;
    o.x = acc.x * d + b.x;
    o.y = acc.y * d + b.y;
    o.z = acc.z * d + b.z;
    o.w = acc.w * d + b.w;
    ((float4*)(out + (size_t)n * N_CH))[lane] = o;
}

extern "C" void kernel_launch(void* const* d_in, const int* in_sizes, int n_in,
                              void* d_out, int out_size, void* d_ws, size_t ws_size,
                              hipStream_t stream) {
    const int*   row  = (const int*)d_in[0];
    const int*   col  = (const int*)d_in[1];
    const float* vals = (const float*)d_in[2];
    const float* X    = (const float*)d_in[3];
    const float* W    = (const float*)d_in[4];
    const float* bias = (const float*)d_in[5];
    float* out = (float*)d_out;

    const int E = in_sizes[0];
    const int N = in_sizes[3] / N_CH;
    const int nb = (N + 255) / 256;

    // workspace layout (8-byte aligned first)
    uint2*          epack = (uint2*)d_ws;                       // E uint2
    unsigned short* Ybf   = (unsigned short*)(epack + E);       // N*128 bf16
    float*          dinv  = (float*)(Ybf + (size_t)N * N_CH);   // N f32
    int*            cnt   = (int*)(dinv + N);                   // N i32
    int*            pos   = cnt + N;                            // N i32
    int*            rank  = pos + N;                            // E i32
    int*            bsum  = rank + E;                           // nb i32
    unsigned short* Wt    = (unsigned short*)(bsum + nb);       // 128*128 bf16

    hipMemsetAsync(cnt, 0, (size_t)N * sizeof(int), stream);

    rank_kernel<<<(E + 2047) / 2048, 256, 0, stream>>>(row, cnt, rank, E);
    scan1_kernel<<<nb, 256, 0, stream>>>(cnt, pos, bsum, N);
    scan2_kernel<<<1, 512, 0, stream>>>(bsum, nb);
    scan3_kernel<<<nb, 256, 0, stream>>>(pos, bsum, N, W, Wt);
    place_kernel<<<(E + 1023) / 1024, 256, 0, stream>>>(row, col, vals, pos, rank, epack, E);
    dinv_kernel<<<nb, 256, 0, stream>>>(pos, epack, dinv, N, E);

    int tiles = N / 16;                      // N divisible by 16 (100000)
    int gblocks = (tiles + 7) / 8;           // 8 tiles per block (4 waves x 2)
    gemm_kernel<<<gblocks, 256, 0, stream>>>(X, Wt, dinv, Ybf, tiles);

    unsigned gth = (unsigned)N * 32u;
    gather_kernel<<<(gth + 255) / 256, 256, 0, stream>>>(pos, epack, Ybf, dinv, bias, out, N, E);
}